// Round 3
// baseline (19086.774 us; speedup 1.0000x reference)
//
#include <hip/hip_runtime.h>
#include <math.h>

#define NUME 30000
#define DIM_IN 128
#define DIM_OUT 128
#define DIM_R 64
#define DIM_T 32
#define HEADS 4
#define DHEAD 32
#define R_TOTAL 17
#define N_NODES 20000
#define N_EDGES 15000
#define DIN 160
#define NEG_SLOPE 0.2f
#define ECOLS 136           /* 17 relations * (el,er) * 4 heads packed */
#define NKEY (R_TOTAL * N_NODES)   /* 340000 softmax segments */
#define NE_ALL (R_TOTAL * N_EDGES) /* 255000 */

typedef __attribute__((ext_vector_type(8))) unsigned short ushort8;

// ---- bf16 via explicit bits (round-to-nearest-even) ----
__device__ __forceinline__ unsigned short f2bf(float f){
  unsigned u = __float_as_uint(f);
  return (unsigned short)((u + 0x7FFFu + ((u >> 16) & 1u)) >> 16);
}
__device__ __forceinline__ float bf2f(unsigned short b){
  return __uint_as_float((unsigned)b << 16);
}

// ---- build x = [entity_emb[nid % NUME] | cos(dt*freq + phase)] ----
__global__ __launch_bounds__(256) void k_build_x(const int* node_ids, const float* entity_emb,
                                                 const float* basis_freq, const float* phase,
                                                 const int* ts_p, float* x){
  int i = blockIdx.x * 256 + threadIdx.x;
  if (i >= N_NODES * DIN) return;
  int n = i / DIN, c = i % DIN;
  int nid = node_ids[n];
  if (c < DIM_IN){
    x[i] = entity_emb[(size_t)(nid % NUME) * DIM_IN + c];
  } else {
    int t = c - DIM_IN;
    float dt = (float)(ts_p[0] - 1 - nid / NUME);
    x[i] = cosf(dt * basis_freq[t] + phase[t]);
  }
}

// ---- wa[l][k][r*8 + side*4 + h] = sum_d w[l,r,k,h*32+d] * attn_{side}[l,r,h,d] ----
__global__ __launch_bounds__(256) void k_wa(const float* fc_w, const float* attn_l,
                                            const float* attn_r, float* wa){
  int lr = blockIdx.x;            // l*17 + r
  int l = lr / R_TOTAL, r = lr % R_TOTAL;
  const float* w  = fc_w  + (size_t)lr * DIN * DIM_OUT;
  const float* al = attn_l + (size_t)lr * HEADS * DHEAD;
  const float* ar = attn_r + (size_t)lr * HEADS * DHEAD;
  for (int i = threadIdx.x; i < DIN * HEADS; i += 256){
    int k = i / HEADS, h = i % HEADS;
    float sl = 0.f, sr = 0.f;
    for (int d = 0; d < DHEAD; ++d){
      float wv = w[(size_t)k * DIM_OUT + h * DHEAD + d];
      sl += wv * al[h * DHEAD + d];
      sr += wv * ar[h * DHEAD + d];
    }
    wa[((size_t)l * DIN + k) * ECOLS + r * 8 + h]     = sl;
    wa[((size_t)l * DIN + k) * ECOLS + r * 8 + 4 + h] = sr;
  }
}

// ============ CSR build over key = r*N_NODES + dst (graph is layer-invariant) ============
__global__ __launch_bounds__(256) void k_zero_count(int* count){
  int i = blockIdx.x * 256 + threadIdx.x;
  if (i < NKEY) count[i] = 0;
}
__global__ __launch_bounds__(256) void k_count(const int* edge_dst, int* count){
  int i = blockIdx.x * 256 + threadIdx.x;
  if (i >= NE_ALL) return;
  int r = i / N_EDGES;
  atomicAdd(&count[r * N_NODES + edge_dst[i]], 1);
}
// single-block exclusive scan of count[NKEY] -> row_start[NKEY+1]
__global__ __launch_bounds__(1024) void k_scan(const int* count, int* row_start){
  __shared__ int part[1024];
  int t = threadIdx.x;
  const int CH = (NKEY + 1023) / 1024;   // 333
  int base = t * CH;
  int s = 0;
  for (int i = 0; i < CH; ++i){
    int idx = base + i;
    if (idx < NKEY) s += count[idx];
  }
  part[t] = s;
  __syncthreads();
  for (int off = 1; off < 1024; off <<= 1){
    int v = (t >= off) ? part[t - off] : 0;
    __syncthreads();
    part[t] += v;
    __syncthreads();
  }
  int excl = (t == 0) ? 0 : part[t - 1];
  for (int i = 0; i < CH; ++i){
    int idx = base + i;
    if (idx <= NKEY) row_start[idx] = excl;
    if (idx < NKEY) excl += count[idx];
  }
}
__global__ __launch_bounds__(256) void k_copy_cursor(const int* row_start, int* cursor){
  int i = blockIdx.x * 256 + threadIdx.x;
  if (i < NKEY) cursor[i] = row_start[i];
}
__global__ __launch_bounds__(256) void k_fill(const int* edge_dst, int* cursor, int* eidlist){
  int i = blockIdx.x * 256 + threadIdx.x;
  if (i >= NE_ALL) return;
  int r = i / N_EDGES;
  int key = r * N_NODES + edge_dst[i];
  int pos = atomicAdd(&cursor[key], 1);
  eidlist[pos] = i;
}

// ---- elr = x @ wa[l]  (20000x160)@(160x136): el/er for all relations/heads ----
__global__ __launch_bounds__(256) void k_elr(const float* x, const float* wa, float* elr, int l){
  __shared__ float sX[64][33];
  __shared__ float sWA[32][ECOLS];
  int n0 = blockIdx.x * 64;
  int tid = threadIdx.x;
  int nt = tid & 31, ct = tid >> 5;       // ct 0..7 -> cols ct*17..+16
  float acc[2][17] = {};
  for (int kc = 0; kc < 5; ++kc){
    __syncthreads();
    for (int i = tid; i < 64 * 32; i += 256){
      int nn = i >> 5, kk = i & 31;
      int n = n0 + nn;
      sX[nn][kk] = (n < N_NODES) ? x[(size_t)n * DIN + kc * 32 + kk] : 0.f;
    }
    for (int i = tid; i < 32 * ECOLS; i += 256){
      int kk = i / ECOLS, c = i % ECOLS;
      sWA[kk][c] = wa[((size_t)l * DIN + kc * 32 + kk) * ECOLS + c];
    }
    __syncthreads();
    for (int kk = 0; kk < 32; ++kk){
      float x0 = sX[nt][kk], x1 = sX[nt + 32][kk];
      #pragma unroll
      for (int j = 0; j < 17; ++j){
        float wv = sWA[kk][ct * 17 + j];
        acc[0][j] += x0 * wv;
        acc[1][j] += x1 * wv;
      }
    }
  }
  #pragma unroll
  for (int q = 0; q < 2; ++q){
    int n = n0 + nt + q * 32;
    if (n < N_NODES)
      for (int j = 0; j < 17; ++j)
        elr[(size_t)n * ECOLS + ct * 17 + j] = acc[q][j];
  }
}

// ---- per-edge logits e = leakyrelu(el[src]+er[dst])  (no atomics) ----
__global__ __launch_bounds__(256) void k_edge_e(const int* edge_src, const int* edge_dst,
                                                const float* elr, float* e_edge){
  int i = blockIdx.x * 256 + threadIdx.x;
  if (i >= NE_ALL) return;
  int r = i / N_EDGES;
  int s = edge_src[i], d = edge_dst[i];
  const float* el = &elr[(size_t)s * ECOLS + r * 8];
  const float* er = &elr[(size_t)d * ECOLS + r * 8 + 4];
  #pragma unroll
  for (int h = 0; h < 4; ++h){
    float v = el[h] + er[h];
    v = v >= 0.f ? v : NEG_SLOPE * v;
    e_edge[(size_t)i * 4 + h] = v;
  }
}

// ---- segment softmax per (key, head) via CSR: writes alpha per (edge, head) ----
__global__ __launch_bounds__(256) void k_soft(const int* row_start, const int* eidlist,
                                              const float* e_edge, float* alpha){
  int i = blockIdx.x * 256 + threadIdx.x;
  if (i >= NKEY * HEADS) return;
  int key = i >> 2, h = i & 3;
  int b = row_start[key], e = row_start[key + 1];
  if (b == e) return;
  float m = -INFINITY;
  for (int idx = b; idx < e; ++idx)
    m = fmaxf(m, e_edge[(size_t)eidlist[idx] * 4 + h]);
  float den = 0.f;
  for (int idx = b; idx < e; ++idx){
    float ex = expf(e_edge[(size_t)eidlist[idx] * 4 + h] - m);
    alpha[(size_t)eidlist[idx] * 4 + h] = ex;
    den += ex;
  }
  float inv = 1.f / fmaxf(den, 1e-9f);
  for (int idx = b; idx < e; ++idx)
    alpha[(size_t)eidlist[idx] * 4 + h] *= inv;
}

// ---- message GEMM: msg[(r,e)][c] = alpha[e][head(c)] * (x[src_e] @ w[l,r])[c], bf16 store ----
#define EB 64
__global__ __launch_bounds__(256) void k_msg(const int* edge_src, const float* x,
                                             const float* fc_w, const float* alpha,
                                             unsigned short* msg, int l){
  __shared__ float sX[EB][161];
  __shared__ float sW[32][128];
  __shared__ float sAl[EB][4];
  __shared__ int sSrc[EB];
  int r = blockIdx.y;
  int e0 = blockIdx.x * EB;
  int tid = threadIdx.x;

  if (tid < EB){
    int e = e0 + tid;
    sSrc[tid] = (e < N_EDGES) ? edge_src[(size_t)r * N_EDGES + e] : 0;
  }
  {
    int e = e0 + (tid >> 2), h = tid & 3;   // 256 threads = 64 edges * 4 heads
    float a = 0.f;
    if (e < N_EDGES)
      a = alpha[((size_t)r * N_EDGES + e) * 4 + h];
    sAl[tid >> 2][h] = a;
  }
  __syncthreads();
  for (int i = tid; i < EB * DIN; i += 256){
    int e = i / DIN, k = i % DIN;
    sX[e][k] = x[(size_t)sSrc[e] * DIN + k];
  }

  const float* w = fc_w + ((size_t)(l * R_TOTAL + r)) * DIN * DIM_OUT;
  int eg = tid >> 4;   // 0..15 -> edges eg*4..+3
  int cg = tid & 15;   // 0..15 -> cols  cg*8..+7
  float acc[4][8] = {};
  for (int kc = 0; kc < 5; ++kc){
    __syncthreads();
    for (int i = tid; i < 32 * 32; i += 256){        // 32 rows x 32 float4
      int kk = i >> 5, c4 = i & 31;
      *(float4*)&sW[kk][c4 * 4] = *(const float4*)&w[(size_t)(kc * 32 + kk) * DIM_OUT + c4 * 4];
    }
    __syncthreads();
    for (int kk = 0; kk < 32; ++kk){
      float4 w0 = *(float4*)&sW[kk][cg * 8];
      float4 w1 = *(float4*)&sW[kk][cg * 8 + 4];
      #pragma unroll
      for (int i2 = 0; i2 < 4; ++i2){
        float xv = sX[eg * 4 + i2][kc * 32 + kk];
        acc[i2][0] += xv * w0.x; acc[i2][1] += xv * w0.y;
        acc[i2][2] += xv * w0.z; acc[i2][3] += xv * w0.w;
        acc[i2][4] += xv * w1.x; acc[i2][5] += xv * w1.y;
        acc[i2][6] += xv * w1.z; acc[i2][7] += xv * w1.w;
      }
    }
  }
  #pragma unroll
  for (int i2 = 0; i2 < 4; ++i2){
    int e = eg * 4 + i2;
    if (e0 + e < N_EDGES){
      float a = sAl[e][cg >> 2];   // head = (cg*8)/32; 8 cols stay in one head
      ushort8 v;
      #pragma unroll
      for (int j = 0; j < 8; ++j)
        v[j] = f2bf(a * acc[i2][j]);
      *(ushort8*)&msg[((size_t)r * N_EDGES + e0 + e) * DIM_OUT + cg * 8] = v;
    }
  }
}

// ---- gather: h[n][c] = relu(mean_r sum_{e in seg(r,n)} msg[e][c]); write into x[:, :128] ----
__global__ __launch_bounds__(256) void k_gather(const int* row_start, const int* eidlist,
                                                const unsigned short* msg, float* x){
  int tid = threadIdx.x;
  int n = blockIdx.x * 2 + (tid >> 7);
  int c = tid & 127;
  if (n >= N_NODES) return;
  float acc = 0.f;
  for (int r = 0; r < R_TOTAL; ++r){
    int key = r * N_NODES + n;
    int b = row_start[key], e = row_start[key + 1];
    for (int idx = b; idx < e; ++idx)
      acc += bf2f(msg[(size_t)eidlist[idx] * DIM_OUT + c]);
  }
  x[(size_t)n * DIN + c] = fmaxf(acc * (1.0f / 17.0f), 0.f);
}

// ---- A_cat: rows 0..1023 = [h[root[1024+b]] | obj_rel_emb[rel[b]]] (feeds sub_pred)
//             rows 1024..2047 = [h[root[b]] | sub_rel_emb[rel[b]]]   (feeds obj_pred)
__global__ __launch_bounds__(256) void k_cat(const int* root_idx, const int* rel, const float* x,
                                             const float* sub_rel_emb, const float* obj_rel_emb,
                                             float* A){
  int i = blockIdx.x * 256 + threadIdx.x;
  if (i >= 2048 * 192) return;
  int row = i / 192, k = i % 192;
  int b = row & 1023;
  bool top = row < 1024;    // sub_pred rows
  float v;
  if (k < 128){
    int node = root_idx[top ? (1024 + b) : b];
    v = x[(size_t)node * DIN + k];
  } else {
    const float* re = top ? obj_rel_emb : sub_rel_emb;
    v = re[(size_t)rel[b] * DIM_R + (k - 128)];
  }
  A[i] = v;
}

// ---- classifier GEMM: (2048x192)@(192x30000), rows<1024 use sub_cls, else obj_cls ----
__global__ __launch_bounds__(256) void k_cls(const float* A, const float* w_sub, const float* b_sub,
                                             const float* w_obj, const float* b_obj, float* out){
  __shared__ float sA[64][33];
  __shared__ float sW[32][128];
  int rb = blockIdx.y, cb = blockIdx.x;
  int row0 = rb * 64, col0 = cb * 128;
  const float* w    = (rb < 16) ? w_sub : w_obj;
  const float* bias = (rb < 16) ? b_sub : b_obj;
  int tid = threadIdx.x;
  int tr = tid >> 5, tc = tid & 31;   // 8 rows x 4 cols per thread
  float acc[8][4] = {};
  for (int kc = 0; kc < 6; ++kc){
    __syncthreads();
    for (int i = tid; i < 64 * 32; i += 256){
      int rr = i >> 5, kk = i & 31;
      sA[rr][kk] = A[(size_t)(row0 + rr) * 192 + kc * 32 + kk];
    }
    for (int i = tid; i < 32 * 32; i += 256){
      int kk = i >> 5, c4 = i & 31;
      int col = col0 + c4 * 4;
      float4 v = make_float4(0.f, 0.f, 0.f, 0.f);
      if (col < 30000) v = *(const float4*)&w[(size_t)(kc * 32 + kk) * 30000 + col];
      *(float4*)&sW[kk][c4 * 4] = v;
    }
    __syncthreads();
    for (int kk = 0; kk < 32; ++kk){
      float4 wv = *(float4*)&sW[kk][tc * 4];
      #pragma unroll
      for (int i2 = 0; i2 < 8; ++i2){
        float av = sA[tr * 8 + i2][kk];
        acc[i2][0] += av * wv.x; acc[i2][1] += av * wv.y;
        acc[i2][2] += av * wv.z; acc[i2][3] += av * wv.w;
      }
    }
  }
  int col = col0 + tc * 4;
  if (col < 30000){
    float4 bv = *(const float4*)&bias[col];
    #pragma unroll
    for (int i2 = 0; i2 < 8; ++i2){
      int row = row0 + tr * 8 + i2;
      float4 o = make_float4(acc[i2][0] + bv.x, acc[i2][1] + bv.y,
                             acc[i2][2] + bv.z, acc[i2][3] + bv.w);
      *(float4*)&out[(size_t)row * 30000 + col] = o;
    }
  }
}

extern "C" void kernel_launch(void* const* d_in, const int* in_sizes, int n_in,
                              void* d_out, int out_size, void* d_ws, size_t ws_size,
                              hipStream_t stream){
  const int*   node_ids    = (const int*)  d_in[0];
  const int*   edge_src    = (const int*)  d_in[1];
  const int*   edge_dst    = (const int*)  d_in[2];
  const int*   root_idx    = (const int*)  d_in[3];
  const int*   rel         = (const int*)  d_in[4];
  const float* entity_emb  = (const float*)d_in[5];
  const float* basis_freq  = (const float*)d_in[6];
  const float* phase       = (const float*)d_in[7];
  const float* fc_w        = (const float*)d_in[8];
  const float* attn_l      = (const float*)d_in[9];
  const float* attn_r      = (const float*)d_in[10];
  const float* sub_rel_emb = (const float*)d_in[11];
  const float* obj_rel_emb = (const float*)d_in[12];
  const float* sub_cls_w   = (const float*)d_in[13];
  const float* sub_cls_b   = (const float*)d_in[14];
  const float* obj_cls_w   = (const float*)d_in[15];
  const float* obj_cls_b   = (const float*)d_in[16];
  const int*   ts_p        = (const int*)  d_in[17];
  float* out = (float*)d_out;

  char* p = (char*)d_ws;
  auto alloc = [&](size_t bytes) -> char* {
    char* q = p; p += (bytes + 255) & ~(size_t)255; return q;
  };
  float*    x        = (float*)   alloc((size_t)N_NODES * DIN * 4);
  float*    elr      = (float*)   alloc((size_t)N_NODES * ECOLS * 4);
  float*    e_edge   = (float*)   alloc((size_t)NE_ALL * HEADS * 4);
  float*    alpha    = (float*)   alloc((size_t)NE_ALL * HEADS * 4);
  int*      count    = (int*)     alloc((size_t)NKEY * 4);
  int*      row_start= (int*)     alloc((size_t)(NKEY + 1) * 4);
  int*      cursor   = (int*)     alloc((size_t)NKEY * 4);
  int*      eidlist  = (int*)     alloc((size_t)NE_ALL * 4);
  float*    wa       = (float*)   alloc((size_t)2 * DIN * ECOLS * 4);
  float*    A_cat    = (float*)   alloc((size_t)2048 * 192 * 4);
  unsigned short* msg = (unsigned short*)alloc((size_t)NE_ALL * DIM_OUT * 2);

  // CSR build (graph identical for both layers)
  k_zero_count<<<(NKEY + 255) / 256, 256, 0, stream>>>(count);
  k_count<<<(NE_ALL + 255) / 256, 256, 0, stream>>>(edge_dst, count);
  k_scan<<<1, 1024, 0, stream>>>(count, row_start);
  k_copy_cursor<<<(NKEY + 255) / 256, 256, 0, stream>>>(row_start, cursor);
  k_fill<<<(NE_ALL + 255) / 256, 256, 0, stream>>>(edge_dst, cursor, eidlist);

  k_wa<<<2 * R_TOTAL, 256, 0, stream>>>(fc_w, attn_l, attn_r, wa);
  k_build_x<<<(N_NODES * DIN + 255) / 256, 256, 0, stream>>>(node_ids, entity_emb, basis_freq,
                                                             phase, ts_p, x);
  for (int l = 0; l < 2; ++l){
    k_elr<<<(N_NODES + 63) / 64, 256, 0, stream>>>(x, wa, elr, l);
    k_edge_e<<<(NE_ALL + 255) / 256, 256, 0, stream>>>(edge_src, edge_dst, elr, e_edge);
    k_soft<<<(NKEY * HEADS + 255) / 256, 256, 0, stream>>>(row_start, eidlist, e_edge, alpha);
    k_msg<<<dim3((N_EDGES + EB - 1) / EB, R_TOTAL), 256, 0, stream>>>(edge_src, x, fc_w,
                                                                      alpha, msg, l);
    k_gather<<<(N_NODES + 1) / 2, 256, 0, stream>>>(row_start, eidlist, msg, x);
  }
  k_cat<<<(2048 * 192 + 255) / 256, 256, 0, stream>>>(root_idx, rel, x,
                                                      sub_rel_emb, obj_rel_emb, A_cat);
  k_cls<<<dim3((30000 + 127) / 128, 32), 256, 0, stream>>>(A_cat, sub_cls_w, sub_cls_b,
                                                           obj_cls_w, obj_cls_b, out);
}